// Round 1
// 1487.495 us; speedup vs baseline: 1.0890x; 1.0890x over previous
//
#include <hip/hip_runtime.h>

// CapsAll on MI355X — round 5: global_load_lds staging for k1/k2 GEMMs
// (m93->m97 ladder step, +69% proven on this structure), u-permuted k2
// B-tile so the softmax epilogue reads x as coalesced float4, __expf.
//
// Numerics: identical to round 4 except expf->__expf in k2 (v_exp_f32,
// ~1 ulp; est. +<3e-7 absmax on top of measured 4.8e-7; threshold 1.93e-6).
//
//   k0h: fp32 -> bf16(hi) plane  (W1, W2, and x if ws allows)
//   k0t: cw [r][k][n] fp32 -> cwh/cwl [r][n][k] bf16 (tiled transpose+split)
//   k1:  hbar = relu(x @ WS1_r^T), 1 MFMA pass, global_load_lds staging
//   k2:  scores = Hh @ WS2_r^T (256x64) + fused col-softmax + m,
//        global_load_lds staging, u-permuted B rows -> float4 x loads
//   k3:  votes = m @ cw, 2-pass MFMA (fallback: fp32 VALU kernel)
//   k4:  dynamic routing (3 iters) + norms
//
// ws layout (MB): m 4 @0 | votes 8 @4 | W1h 8 @12 | W2h 8 @20 |
//   [cwh 32 @28 | cwl 32 @60]  if ws>=124 | [Xbf 64 @92] if ws>=188 |
//   Hh 32 @{156|92|28}  (b-chunked if tiny ws)

typedef __attribute__((ext_vector_type(8))) short bf16x8;
typedef __attribute__((ext_vector_type(8))) unsigned short u16x8;
typedef __attribute__((ext_vector_type(4))) float f32x4;

#define LDT 40  // LDS row stride (bf16) for the legacy reg-staged kernels

__device__ __forceinline__ unsigned short f2bf(float f) {
    unsigned u = __float_as_uint(f);
    u += 0x7FFF + ((u >> 16) & 1);           // round-to-nearest-even
    return (unsigned short)(u >> 16);
}
__device__ __forceinline__ float bf2f(unsigned short h) {
    return __uint_as_float(((unsigned)h) << 16);
}

// async global->LDS, 16 B per lane. LDS dest must be wave-uniform base;
// HW scatters lane*16. Global src is per-lane.
typedef __attribute__((address_space(1))) void gvoid;
typedef __attribute__((address_space(3))) void lvoid;
__device__ __forceinline__ void gll16(const unsigned short* g, unsigned short* l) {
    __builtin_amdgcn_global_load_lds((gvoid*)g, (lvoid*)l, 16, 0, 0);
}

// ---------------- k0h: elementwise fp32 -> bf16 hi plane ----------------
__global__ __launch_bounds__(256) void k0_hi(const float* __restrict__ src,
                                             unsigned short* __restrict__ hi,
                                             int n4) {
    int i = blockIdx.x * 256 + threadIdx.x;
    if (i >= n4) return;
    float4 v = ((const float4*)src)[i];
    ushort4 h;
    h.x = f2bf(v.x); h.y = f2bf(v.y); h.z = f2bf(v.z); h.w = f2bf(v.w);
    ((ushort4*)hi)[i] = h;
}

// ------- k0t: cw [r][k=1024][n=2048] fp32 -> [r][n][k] bf16 hi+lo -------
__global__ __launch_bounds__(256) void k0_tsplit(const float* __restrict__ cw,
                                                 unsigned short* __restrict__ ch,
                                                 unsigned short* __restrict__ cl) {
    __shared__ unsigned short Th[64 * 68], Tl[64 * 68];
    const int tid = threadIdx.x;
    const int n0 = blockIdx.x * 64, k0 = blockIdx.y * 64, r = blockIdx.z;
    const float* src = cw + (size_t)r * 1024 * 2048;
#pragma unroll
    for (int p = 0; p < 4; p++) {
        const int kl = p * 16 + (tid >> 4);
        const int nl = (tid & 15) * 4;
        float4 v = *(const float4*)(src + (size_t)(k0 + kl) * 2048 + n0 + nl);
        float vv[4] = {v.x, v.y, v.z, v.w};
#pragma unroll
        for (int e = 0; e < 4; e++) {
            unsigned short h = f2bf(vv[e]);
            Th[(nl + e) * 68 + kl] = h;
            Tl[(nl + e) * 68 + kl] = f2bf(vv[e] - bf2f(h));
        }
    }
    __syncthreads();
    const int nl = tid >> 2, kl = (tid & 3) * 16;
    unsigned short* dh = ch + ((size_t)r * 2048 + n0 + nl) * 1024 + k0 + kl;
    unsigned short* dl = cl + ((size_t)r * 2048 + n0 + nl) * 1024 + k0 + kl;
    *(u16x8*)(dh)     = *(const u16x8*)&Th[nl * 68 + kl];
    *(u16x8*)(dh + 8) = *(const u16x8*)&Th[nl * 68 + kl + 8];
    *(u16x8*)(dl)     = *(const u16x8*)&Tl[nl * 68 + kl];
    *(u16x8*)(dl + 8) = *(const u16x8*)&Tl[nl * 68 + kl + 8];
}

// -------- k1 (gll): hbar = relu(Xbf @ W1^T), global_load_lds staging ----
// 128x128 tile, BK=32, 4 waves (2x2 of 64x64). Linear LDS [row][32] bf16.
__global__ __launch_bounds__(256) void k1_hbar_gll(
    const unsigned short* __restrict__ Xb,
    const unsigned short* __restrict__ Wh,
    unsigned short* __restrict__ Hh) {
    __shared__ __align__(16) unsigned short Ah[128 * 32];  // 8 KB
    __shared__ __align__(16) unsigned short Bh[128 * 32];  // 8 KB
    const int tid = threadIdx.x;
    const int m0 = blockIdx.x * 128, n0 = blockIdx.y * 128;
    const int wave = tid >> 6, lane = tid & 63;
    const int wm = (wave >> 1) * 64, wn = (wave & 1) * 64;
    const int lx = lane & 15, qd = lane >> 4;
    const int rl = lane >> 2, cl = (lane & 3) * 8;   // 16 rows/KB, 16B/lane

    f32x4 acc[4][4];
#pragma unroll
    for (int i = 0; i < 4; i++)
#pragma unroll
        for (int j = 0; j < 4; j++) acc[i][j] = (f32x4){0.f, 0.f, 0.f, 0.f};

    const unsigned short* asrc = Xb + (size_t)(m0 + rl) * 1024 + cl;
    const unsigned short* bsrc = Wh + (size_t)(n0 + rl) * 1024 + cl;

    for (int k0 = 0; k0 < 1024; k0 += 32) {
#pragma unroll
        for (int s = 0; s < 2; s++) {
            const int c = wave * 2 + s;              // 8 chunks of 16 rows
            gll16(asrc + (size_t)c * 16 * 1024 + k0, &Ah[c * 512]);
            gll16(bsrc + (size_t)c * 16 * 1024 + k0, &Bh[c * 512]);
        }
        __syncthreads();                             // drains vmcnt
        bf16x8 fa[4], fb[4];
#pragma unroll
        for (int i = 0; i < 4; i++) {
            fa[i] = *(const bf16x8*)&Ah[(wm + 16 * i + lx) * 32 + 8 * qd];
            fb[i] = *(const bf16x8*)&Bh[(wn + 16 * i + lx) * 32 + 8 * qd];
        }
#pragma unroll
        for (int i = 0; i < 4; i++)
#pragma unroll
            for (int j = 0; j < 4; j++)
                acc[i][j] = __builtin_amdgcn_mfma_f32_16x16x32_bf16(fa[i], fb[j], acc[i][j], 0, 0, 0);
        __syncthreads();
    }

#pragma unroll
    for (int i = 0; i < 4; i++)
#pragma unroll
        for (int j = 0; j < 4; j++) {
            const int col = n0 + wn + 16 * j + lx;
#pragma unroll
            for (int p = 0; p < 4; p++) {
                const int row = m0 + wm + 16 * i + 4 * qd + p;
                Hh[(size_t)row * 512 + col] = f2bf(fmaxf(acc[i][j][p], 0.f));
            }
        }
}

// ---- k1 fallback (fp32 x, reg-staged): unchanged round-4 kernel --------
template <int XBF>
__global__ __launch_bounds__(256) void k1_hbar_mfma(
    const void* __restrict__ Xv,
    const unsigned short* __restrict__ Wh,
    unsigned short* __restrict__ Hh) {
    __shared__ unsigned short Ah[128 * LDT];
    __shared__ unsigned short Bh[128 * LDT];
    const int tid = threadIdx.x;
    const int m0 = blockIdx.x * 128, n0 = blockIdx.y * 128;
    const int wave = tid >> 6, lane = tid & 63;
    const int wm = (wave >> 1) * 64, wn = (wave & 1) * 64;
    const int lx = lane & 15, qd = lane >> 4;
    const int srow = tid >> 1, scol = (tid & 1) * 16;

    f32x4 acc[4][4];
#pragma unroll
    for (int i = 0; i < 4; i++)
#pragma unroll
        for (int j = 0; j < 4; j++) acc[i][j] = (f32x4){0.f, 0.f, 0.f, 0.f};

    const unsigned short* whrow = Wh + (size_t)(n0 + srow) * 1024 + scol;
    unsigned short* ah = &Ah[srow * LDT + scol];
    unsigned short* bh = &Bh[srow * LDT + scol];

    for (int k0 = 0; k0 < 1024; k0 += 32) {
        if (XBF) {
            const unsigned short* xrow =
                (const unsigned short*)Xv + (size_t)(m0 + srow) * 1024 + scol;
            u16x8 a0 = *(const u16x8*)(xrow + k0);
            u16x8 a1 = *(const u16x8*)(xrow + k0 + 8);
            *(u16x8*)(ah) = a0; *(u16x8*)(ah + 8) = a1;
        } else {
            const float* xrow = (const float*)Xv + (size_t)(m0 + srow) * 1024 + scol;
            float4 v0 = *(const float4*)(xrow + k0);
            float4 v1 = *(const float4*)(xrow + k0 + 4);
            float4 v2 = *(const float4*)(xrow + k0 + 8);
            float4 v3 = *(const float4*)(xrow + k0 + 12);
            float vv[16] = {v0.x, v0.y, v0.z, v0.w, v1.x, v1.y, v1.z, v1.w,
                            v2.x, v2.y, v2.z, v2.w, v3.x, v3.y, v3.z, v3.w};
            u16x8 p0, p1;
#pragma unroll
            for (int e = 0; e < 8; e++) p0[e] = f2bf(vv[e]);
#pragma unroll
            for (int e = 0; e < 8; e++) p1[e] = f2bf(vv[8 + e]);
            *(u16x8*)(ah) = p0; *(u16x8*)(ah + 8) = p1;
        }
        u16x8 b0 = *(const u16x8*)(whrow + k0);
        u16x8 b1 = *(const u16x8*)(whrow + k0 + 8);
        *(u16x8*)(bh) = b0; *(u16x8*)(bh + 8) = b1;
        __syncthreads();

        bf16x8 fa[4], fb[4];
#pragma unroll
        for (int i = 0; i < 4; i++) {
            fa[i] = *(const bf16x8*)&Ah[(wm + 16 * i + lx) * LDT + 8 * qd];
            fb[i] = *(const bf16x8*)&Bh[(wn + 16 * i + lx) * LDT + 8 * qd];
        }
#pragma unroll
        for (int i = 0; i < 4; i++)
#pragma unroll
            for (int j = 0; j < 4; j++)
                acc[i][j] = __builtin_amdgcn_mfma_f32_16x16x32_bf16(fa[i], fb[j], acc[i][j], 0, 0, 0);
        __syncthreads();
    }

#pragma unroll
    for (int i = 0; i < 4; i++)
#pragma unroll
        for (int j = 0; j < 4; j++) {
            const int col = n0 + wn + 16 * j + lx;
#pragma unroll
            for (int p = 0; p < 4; p++) {
                const int row = m0 + wm + 16 * i + 4 * qd + p;
                Hh[(size_t)row * 512 + col] = f2bf(fmaxf(acc[i][j][p], 0.f));
            }
        }
}

// ------- k2: scores (256x64) + column softmax over t + m ----------------
// global_load_lds staging, linear LDS [row][32] bf16. B rows staged with
// the u-permutation c -> u0 + 4*(c&15) + (c>>4): internal col 16j+lx is
// actual u0+4*lx+j, so the epilogue x read is one coalesced float4/lane.
__global__ __launch_bounds__(256) void k2_mfma(
    const unsigned short* __restrict__ Hh,
    const unsigned short* __restrict__ W2h,
    const float* __restrict__ x, float* __restrict__ m_out, int b0, int r) {
    __shared__ __align__(16) unsigned short Ah[256 * 32];  // 16 KB
    __shared__ __align__(16) unsigned short Bh[64 * 32];   // 4 KB
    __shared__ float mred[256], sred[256], pred[256];
    const int tid = threadIdx.x;
    const int b_local = blockIdx.x, b = b0 + b_local;
    const int u0 = blockIdx.y * 64;
    const int wave = tid >> 6, lane = tid & 63;
    const int lx = lane & 15, qd = lane >> 4;
    const int rl = lane >> 2, cl = (lane & 3) * 8;

    f32x4 acc[4][4];
#pragma unroll
    for (int i = 0; i < 4; i++)
#pragma unroll
        for (int j = 0; j < 4; j++) acc[i][j] = (f32x4){0.f, 0.f, 0.f, 0.f};

    const unsigned short* asrc = Hh + (size_t)(b_local * 256 + rl) * 512 + cl;
    const int ub = wave * 16 + rl;                       // B LDS row this lane fills
    const unsigned short* bsrc =
        W2h + (size_t)(u0 + 4 * (ub & 15) + (ub >> 4)) * 512 + cl;

    for (int k0 = 0; k0 < 512; k0 += 32) {
#pragma unroll
        for (int s = 0; s < 4; s++) {
            const int c = wave * 4 + s;                  // 16 chunks of 16 rows
            gll16(asrc + (size_t)c * 16 * 512 + k0, &Ah[c * 512]);
        }
        gll16(bsrc + k0, &Bh[wave * 512]);               // 4 chunks, 1/wave
        __syncthreads();
        bf16x8 fa[4], fb[4];
#pragma unroll
        for (int i = 0; i < 4; i++) {
            fa[i] = *(const bf16x8*)&Ah[(64 * wave + 16 * i + lx) * 32 + 8 * qd];
            fb[i] = *(const bf16x8*)&Bh[(16 * i + lx) * 32 + 8 * qd];
        }
#pragma unroll
        for (int i = 0; i < 4; i++)
#pragma unroll
            for (int j = 0; j < 4; j++)
                acc[i][j] = __builtin_amdgcn_mfma_f32_16x16x32_bf16(fa[i], fb[j], acc[i][j], 0, 0, 0);
        __syncthreads();
    }

    // ---- column max over t: per-lane -> cross-quad -> cross-wave ----
    float cm[4];
#pragma unroll
    for (int j = 0; j < 4; j++) {
        float mx = acc[0][j][0];
#pragma unroll
        for (int i = 0; i < 4; i++)
#pragma unroll
            for (int p = 0; p < 4; p++) mx = fmaxf(mx, acc[i][j][p]);
        mx = fmaxf(mx, __shfl_xor(mx, 16, 64));
        mx = fmaxf(mx, __shfl_xor(mx, 32, 64));
        if (qd == 0) mred[wave * 64 + 16 * j + lx] = mx;
    }
    __syncthreads();
#pragma unroll
    for (int j = 0; j < 4; j++) {
        const int c = 16 * j + lx;
        cm[j] = fmaxf(fmaxf(mred[c], mred[64 + c]), fmaxf(mred[128 + c], mred[192 + c]));
    }

    // ---- exp + weighted sum against x (float4: cols u0+4lx..u0+4lx+3) ----
    float ds[4] = {0.f, 0.f, 0.f, 0.f}, pm[4] = {0.f, 0.f, 0.f, 0.f};
    const float* xb = x + (size_t)b * 256 * 1024 + u0 + 4 * lx;
#pragma unroll
    for (int i = 0; i < 4; i++) {
#pragma unroll
        for (int p = 0; p < 4; p++) {
            const int t = 64 * wave + 16 * i + 4 * qd + p;
            float4 xv = *(const float4*)(xb + (size_t)t * 1024);
            float xa[4] = {xv.x, xv.y, xv.z, xv.w};
#pragma unroll
            for (int j = 0; j < 4; j++) {
                float e = __expf(acc[i][j][p] - cm[j]);
                ds[j] += e;
                pm[j] += e * xa[j];
            }
        }
    }
#pragma unroll
    for (int j = 0; j < 4; j++) {
        ds[j] += __shfl_xor(ds[j], 16, 64);
        ds[j] += __shfl_xor(ds[j], 32, 64);
        pm[j] += __shfl_xor(pm[j], 16, 64);
        pm[j] += __shfl_xor(pm[j], 32, 64);
        if (qd == 0) {
            sred[wave * 64 + 16 * j + lx] = ds[j];
            pred[wave * 64 + 16 * j + lx] = pm[j];
        }
    }
    __syncthreads();
    if (tid < 64) {
        float dsum = sred[tid] + sred[64 + tid] + sred[128 + tid] + sred[192 + tid];
        float psum = pred[tid] + pred[64 + tid] + pred[128 + tid] + pred[192 + tid];
        const int u = u0 + 4 * (tid & 15) + (tid >> 4);  // un-permute
        m_out[(size_t)(r * 128 + b) * 1024 + u] = psum / dsum;
    }
}

// ------- k3 (MFMA): votes = m @ cw, cw split [r][n][k] hi/lo, 2-pass -------
__global__ __launch_bounds__(256) void k3_votes_mfma(
    const float* __restrict__ Mb,
    const unsigned short* __restrict__ CWh,
    const unsigned short* __restrict__ CWl,
    float* __restrict__ V) {
    __shared__ unsigned short Ah[128 * LDT];
    __shared__ unsigned short Bh[64 * LDT], Bl[64 * LDT];
    const int tid = threadIdx.x;
    const int r = blockIdx.x, n0 = blockIdx.y * 64;
    const int wave = tid >> 6, lane = tid & 63;
    const int wr = wave >> 1, wc = wave & 1;
    const int lx = lane & 15, qd = lane >> 4;
    const int srow = tid >> 1, scol = (tid & 1) * 16;
    const int brow = tid >> 2, bcol = (tid & 3) * 8;

    const float* arow = Mb + (size_t)(r * 128 + srow) * 1024 + scol;
    const unsigned short* bhrow = CWh + ((size_t)r * 2048 + n0 + brow) * 1024 + bcol;
    const unsigned short* blrow = CWl + ((size_t)r * 2048 + n0 + brow) * 1024 + bcol;

    f32x4 acc[4][2];
#pragma unroll
    for (int i = 0; i < 4; i++)
#pragma unroll
        for (int j = 0; j < 2; j++) acc[i][j] = (f32x4){0.f, 0.f, 0.f, 0.f};

    for (int k0 = 0; k0 < 1024; k0 += 32) {
        float4 v0 = *(const float4*)(arow + k0);
        float4 v1 = *(const float4*)(arow + k0 + 4);
        float4 v2 = *(const float4*)(arow + k0 + 8);
        float4 v3 = *(const float4*)(arow + k0 + 12);
        float vv[16] = {v0.x, v0.y, v0.z, v0.w, v1.x, v1.y, v1.z, v1.w,
                        v2.x, v2.y, v2.z, v2.w, v3.x, v3.y, v3.z, v3.w};
        u16x8 p0, p1;
#pragma unroll
        for (int e = 0; e < 8; e++) p0[e] = f2bf(vv[e]);
#pragma unroll
        for (int e = 0; e < 8; e++) p1[e] = f2bf(vv[8 + e]);
        *(u16x8*)&Ah[srow * LDT + scol] = p0;
        *(u16x8*)&Ah[srow * LDT + scol + 8] = p1;
        *(u16x8*)&Bh[brow * LDT + bcol] = *(const u16x8*)(bhrow + k0);
        *(u16x8*)&Bl[brow * LDT + bcol] = *(const u16x8*)(blrow + k0);
        __syncthreads();

        bf16x8 fa[4], fbh[2], fbl[2];
#pragma unroll
        for (int i = 0; i < 4; i++)
            fa[i] = *(const bf16x8*)&Ah[(64 * wr + 16 * i + lx) * LDT + 8 * qd];
#pragma unroll
        for (int j = 0; j < 2; j++) {
            fbh[j] = *(const bf16x8*)&Bh[(32 * wc + 16 * j + lx) * LDT + 8 * qd];
            fbl[j] = *(const bf16x8*)&Bl[(32 * wc + 16 * j + lx) * LDT + 8 * qd];
        }
#pragma unroll
        for (int i = 0; i < 4; i++)
#pragma unroll
            for (int j = 0; j < 2; j++)
                acc[i][j] = __builtin_amdgcn_mfma_f32_16x16x32_bf16(fa[i], fbh[j], acc[i][j], 0, 0, 0);
#pragma unroll
        for (int i = 0; i < 4; i++)
#pragma unroll
            for (int j = 0; j < 2; j++)
                acc[i][j] = __builtin_amdgcn_mfma_f32_16x16x32_bf16(fa[i], fbl[j], acc[i][j], 0, 0, 0);
        __syncthreads();
    }

#pragma unroll
    for (int i = 0; i < 4; i++)
#pragma unroll
        for (int j = 0; j < 2; j++) {
            const int col = n0 + 32 * wc + 16 * j + lx;
#pragma unroll
            for (int p = 0; p < 4; p++) {
                const int row = 64 * wr + 16 * i + 4 * qd + p;
                V[((size_t)r * 128 + row) * 2048 + col] = acc[i][j][p];
            }
        }
}

// ---------------- k3 fallback: fp32 VALU (small-ws path) ----------------
__global__ __launch_bounds__(256) void k3_votes(const float* __restrict__ Mb,
                                                const float* __restrict__ CW,
                                                float* __restrict__ V) {
    __shared__ float As[16][132];
    __shared__ float Bs[16][132];
    const int tid = threadIdx.x;
    const int r = blockIdx.z;
    const int n0 = blockIdx.x * 128;
    const float* A = Mb + (size_t)r * 128 * 1024;
    const float* Bm = CW + (size_t)r * 1024 * 2048;
    float* C = V + (size_t)r * 128 * 2048;
    const int ty = tid >> 4, tx = tid & 15;
    const int k4 = (tid & 3) * 4, row = tid >> 2;
    const int n4 = (tid & 31) * 4, krow = tid >> 5;

    float acc[8][8];
#pragma unroll
    for (int i = 0; i < 8; i++)
#pragma unroll
        for (int j = 0; j < 8; j++) acc[i][j] = 0.f;

    for (int k0 = 0; k0 < 1024; k0 += 16) {
#pragma unroll
        for (int rr = 0; rr < 2; rr++) {
            const int m = row + rr * 64;
            float4 av = *(const float4*)(A + (size_t)m * 1024 + k0 + k4);
            As[k4 + 0][m] = av.x; As[k4 + 1][m] = av.y;
            As[k4 + 2][m] = av.z; As[k4 + 3][m] = av.w;
            const int k = krow + rr * 8;
            float4 bv = *(const float4*)(Bm + (size_t)(k0 + k) * 2048 + n0 + n4);
            *(float4*)(&Bs[k][n4]) = bv;
        }
        __syncthreads();
#pragma unroll
        for (int k = 0; k < 16; k++) {
            float a[8], b[8];
            *(float4*)(a)     = *(const float4*)(&As[k][ty * 8]);
            *(float4*)(a + 4) = *(const float4*)(&As[k][ty * 8 + 4]);
            *(float4*)(b)     = *(const float4*)(&Bs[k][tx * 8]);
            *(float4*)(b + 4) = *(const float4*)(&Bs[k][tx * 8 + 4]);
#pragma unroll
            for (int i = 0; i < 8; i++)
#pragma unroll
                for (int j = 0; j < 8; j++) acc[i][j] += a[i] * b[j];
        }
        __syncthreads();
    }
#pragma unroll
    for (int i = 0; i < 8; i++) {
        const int m = ty * 8 + i;
#pragma unroll
        for (int j = 0; j < 8; j += 4) {
            float4 v;
            v.x = acc[i][j + 0]; v.y = acc[i][j + 1];
            v.z = acc[i][j + 2]; v.w = acc[i][j + 3];
            *(float4*)(C + (size_t)m * 2048 + n0 + tx * 8 + j) = v;
        }
    }
}

// ---------------- k4: dynamic routing ----------------
__global__ __launch_bounds__(256) void k4_routing(const float* __restrict__ V,
                                                  float* __restrict__ out) {
    __shared__ float logits[8 * 128];
    __shared__ float route[8 * 128];
    __shared__ float preact[128 * 16];
    __shared__ float act[128 * 16];
    __shared__ float fred[128];
    const int b = blockIdx.x, tid = threadIdx.x;
    const float* vb = V + (size_t)b * 2048;

    for (int i = tid; i < 1024; i += 256) logits[i] = 0.f;
    __syncthreads();

    for (int it = 0; it < 3; it++) {
        {
            const int r = tid >> 5, g = tid & 31;
            float l[4];
#pragma unroll
            for (int q = 0; q < 4; q++) l[q] = logits[r * 128 + g + q * 32];
            float mx = fmaxf(fmaxf(l[0], l[1]), fmaxf(l[2], l[3]));
            for (int msk = 16; msk; msk >>= 1) mx = fmaxf(mx, __shfl_xor(mx, msk, 32));
            float e[4], s = 0.f;
#pragma unroll
            for (int q = 0; q < 4; q++) { e[q] = expf(l[q] - mx); s += e[q]; }
            for (int msk = 16; msk; msk >>= 1) s += __shfl_xor(s, msk, 32);
            float inv = 1.f / s;
#pragma unroll
            for (int q = 0; q < 4; q++) route[r * 128 + g + q * 32] = e[q] * inv;
        }
        __syncthreads();
        for (int i = tid; i < 2048; i += 256) {
            const int c = i >> 4;
            float a = 0.f;
#pragma unroll
            for (int r = 0; r < 8; r++)
                a += route[r * 128 + c] * vb[(size_t)r * 128 * 2048 + i];
            preact[i] = a;
        }
        __syncthreads();
        if (tid < 128) {
            float n2 = 0.f;
#pragma unroll
            for (int o = 0; o < 16; o++) { float p = preact[tid * 16 + o]; n2 += p * p; }
            fred[tid] = sqrtf(n2) / (1.f + n2);
        }
        __syncthreads();
        for (int i = tid; i < 2048; i += 256) act[i] = preact[i] * fred[i >> 4];
        __syncthreads();
        for (int i = tid; i < 1024; i += 256) {
            const int r = i >> 7, c = i & 127;
            float d = 0.f;
#pragma unroll
            for (int o = 0; o < 16; o++)
                d += vb[(size_t)r * 128 * 2048 + c * 16 + o] * act[c * 16 + o];
            logits[i] += d;
        }
        __syncthreads();
    }
    if (tid < 128) {
        float n2 = 0.f;
#pragma unroll
        for (int o = 0; o < 16; o++) { float a = act[tid * 16 + o]; n2 += a * a; }
        out[(size_t)b * 128 + tid] = sqrtf(n2);
    }
}

extern "C" void kernel_launch(void* const* d_in, const int* in_sizes, int n_in,
                              void* d_out, int out_size, void* d_ws, size_t ws_size,
                              hipStream_t stream) {
    const float* x   = (const float*)d_in[0];
    const float* WS1 = (const float*)d_in[1];
    const float* WS2 = (const float*)d_in[2];
    const float* cw  = (const float*)d_in[3];
    float* out = (float*)d_out;

    char* ws = (char*)d_ws;
    float* m_buf = (float*)ws;                                      // 4 MiB
    float* votes = (float*)(ws + ((size_t)4 << 20));                // 8 MiB
    unsigned short* W1h = (unsigned short*)(ws + ((size_t)12 << 20)); // 8 MiB
    unsigned short* W2h = (unsigned short*)(ws + ((size_t)20 << 20)); // 8 MiB

    const bool use_cw  = ws_size >= ((size_t)124 << 20);
    const bool use_xbf = ws_size >= ((size_t)188 << 20);
    unsigned short* CWh = (unsigned short*)(ws + ((size_t)28 << 20)); // 32 MiB
    unsigned short* CWl = (unsigned short*)(ws + ((size_t)60 << 20)); // 32 MiB
    unsigned short* Xbf = (unsigned short*)(ws + ((size_t)92 << 20)); // 64 MiB
    const size_t hh_off = use_xbf ? ((size_t)156 << 20)
                        : use_cw  ? ((size_t)92 << 20)
                                  : ((size_t)28 << 20);
    unsigned short* Hh = (unsigned short*)(ws + hh_off);

    int CB = 128;
    {
        const size_t perb = (size_t)256 << 10;  // Hh per batch row
        if (ws_size < hh_off + 128 * perb) {
            size_t avail = (ws_size > hh_off) ? (ws_size - hh_off) : perb;
            CB = (int)(avail / perb);
            if (CB < 1) CB = 1;
            if (CB > 128) CB = 128;
        }
    }

    const int nW4 = (8 * 512 * 1024) / 4;
    k0_hi<<<dim3((nW4 + 255) / 256), dim3(256), 0, stream>>>(WS1, W1h, nW4);
    k0_hi<<<dim3((nW4 + 255) / 256), dim3(256), 0, stream>>>(WS2, W2h, nW4);
    if (use_cw)
        k0_tsplit<<<dim3(32, 16, 8), dim3(256), 0, stream>>>(cw, CWh, CWl);
    if (use_xbf) {
        const int nX4 = (128 * 256 * 1024) / 4;
        k0_hi<<<dim3((nX4 + 255) / 256), dim3(256), 0, stream>>>(x, Xbf, nX4);
    }

    for (int b0 = 0; b0 < 128; b0 += CB) {
        const int bc = (128 - b0 < CB) ? (128 - b0) : CB;
        for (int r = 0; r < 8; r++) {
            if (use_xbf)
                k1_hbar_gll<<<dim3(bc * 2, 4), dim3(256), 0, stream>>>(
                    Xbf + (size_t)b0 * 256 * 1024,
                    W1h + (size_t)r * 512 * 1024, Hh);
            else
                k1_hbar_mfma<0><<<dim3(bc * 2, 4), dim3(256), 0, stream>>>(
                    (const void*)(x + (size_t)b0 * 256 * 1024),
                    W1h + (size_t)r * 512 * 1024, Hh);
            k2_mfma<<<dim3(bc, 16), dim3(256), 0, stream>>>(
                Hh, W2h + (size_t)r * 1024 * 512, x, m_buf, b0, r);
        }
    }
    if (use_cw)
        k3_votes_mfma<<<dim3(8, 32), dim3(256), 0, stream>>>(m_buf, CWh, CWl, votes);
    else
        k3_votes<<<dim3(16, 1, 8), dim3(256), 0, stream>>>(m_buf, cw, votes);
    k4_routing<<<dim3(128), dim3(256), 0, stream>>>(votes, out);
}

// Round 2
// 1232.955 us; speedup vs baseline: 1.3138x; 1.2064x over previous
//
#include <hip/hip_runtime.h>

// CapsAll on MI355X — round 6: (A) r-loop restructure so fp32 x is read
// ~2x total instead of 8x (k1_all batches r in grid-z; k2_allr loops 4 r
// per block with the x slice L2-resident), (B) 2-phase prefetch pipeline
// (T3 minimum: stage next tile before computing current, one barrier/step)
// in both GEMMs.
//
// Numerics: identical operations in identical order vs round 5 (absmax
// expected unchanged at ~4.8e-7).
//
//   k0h: fp32 -> bf16(hi) plane  (W1, W2, x)
//   k0t: cw [r][k][n] fp32 -> cwh/cwl [r][n][k] bf16 (post-loop, overlays Hh)
//   k1_all: hbar = relu(Xbf @ WS1_r^T) for all 8 r (grid z), 2-phase dbuf
//   k2_allr: scores GEMM + col-softmax + m for 4 r per block, 2-phase dbuf,
//            u-permuted B rows -> coalesced float4 x loads (L2-hot across r)
//   k3:  votes = m @ cw, 2-pass MFMA (fallback: fp32 VALU kernel)
//   k4:  dynamic routing (3 iters) + norms
//
// ws layout, big path (>=188 MB): m 4 @0 | votes 8 @4 | W1h 8 @12 |
//   W2h 8 @20 | Xbf 64 @28 | HhA 64 @92 ... after main loop HhA dies and
//   CWh 32 @92 | CWl 32 @124 overlay it.
// Fallback paths (<188 MB) keep the round-4/5 flow unchanged.

typedef __attribute__((ext_vector_type(8))) short bf16x8;
typedef __attribute__((ext_vector_type(8))) unsigned short u16x8;
typedef __attribute__((ext_vector_type(4))) float f32x4;

#define LDT 40  // LDS row stride (bf16) for the legacy reg-staged kernels

__device__ __forceinline__ unsigned short f2bf(float f) {
    unsigned u = __float_as_uint(f);
    u += 0x7FFF + ((u >> 16) & 1);           // round-to-nearest-even
    return (unsigned short)(u >> 16);
}
__device__ __forceinline__ float bf2f(unsigned short h) {
    return __uint_as_float(((unsigned)h) << 16);
}

// async global->LDS, 16 B per lane. LDS dest wave-uniform base; HW scatters
// lane*16. Global src is per-lane.
typedef __attribute__((address_space(1))) void gvoid;
typedef __attribute__((address_space(3))) void lvoid;
__device__ __forceinline__ void gll16(const unsigned short* g, unsigned short* l) {
    __builtin_amdgcn_global_load_lds((gvoid*)g, (lvoid*)l, 16, 0, 0);
}

// ---------------- k0h: elementwise fp32 -> bf16 hi plane ----------------
__global__ __launch_bounds__(256) void k0_hi(const float* __restrict__ src,
                                             unsigned short* __restrict__ hi,
                                             int n4) {
    int i = blockIdx.x * 256 + threadIdx.x;
    if (i >= n4) return;
    float4 v = ((const float4*)src)[i];
    ushort4 h;
    h.x = f2bf(v.x); h.y = f2bf(v.y); h.z = f2bf(v.z); h.w = f2bf(v.w);
    ((ushort4*)hi)[i] = h;
}

// ------- k0t: cw [r][k=1024][n=2048] fp32 -> [r][n][k] bf16 hi+lo -------
__global__ __launch_bounds__(256) void k0_tsplit(const float* __restrict__ cw,
                                                 unsigned short* __restrict__ ch,
                                                 unsigned short* __restrict__ cl) {
    __shared__ unsigned short Th[64 * 68], Tl[64 * 68];
    const int tid = threadIdx.x;
    const int n0 = blockIdx.x * 64, k0 = blockIdx.y * 64, r = blockIdx.z;
    const float* src = cw + (size_t)r * 1024 * 2048;
#pragma unroll
    for (int p = 0; p < 4; p++) {
        const int kl = p * 16 + (tid >> 4);
        const int nl = (tid & 15) * 4;
        float4 v = *(const float4*)(src + (size_t)(k0 + kl) * 2048 + n0 + nl);
        float vv[4] = {v.x, v.y, v.z, v.w};
#pragma unroll
        for (int e = 0; e < 4; e++) {
            unsigned short h = f2bf(vv[e]);
            Th[(nl + e) * 68 + kl] = h;
            Tl[(nl + e) * 68 + kl] = f2bf(vv[e] - bf2f(h));
        }
    }
    __syncthreads();
    const int nl = tid >> 2, kl = (tid & 3) * 16;
    unsigned short* dh = ch + ((size_t)r * 2048 + n0 + nl) * 1024 + k0 + kl;
    unsigned short* dl = cl + ((size_t)r * 2048 + n0 + nl) * 1024 + k0 + kl;
    *(u16x8*)(dh)     = *(const u16x8*)&Th[nl * 68 + kl];
    *(u16x8*)(dh + 8) = *(const u16x8*)&Th[nl * 68 + kl + 8];
    *(u16x8*)(dl)     = *(const u16x8*)&Tl[nl * 68 + kl];
    *(u16x8*)(dl + 8) = *(const u16x8*)&Tl[nl * 68 + kl + 8];
}

// -------- k1_all: hbar = relu(Xbf @ W1_r^T) for all r, 2-phase dbuf -----
// 128x128 tile, BK=32, 4 waves. grid (64 m-tiles, 4 n-tiles, 8 r).
// Linear LDS [row][32] bf16, double buffered.
__global__ __launch_bounds__(256) void k1_all(
    const unsigned short* __restrict__ Xb,   // chunk base [8192][1024]
    const unsigned short* __restrict__ W1h,  // [8][512][1024]
    unsigned short* __restrict__ HhA) {      // [8][8192][512]
    __shared__ __align__(16) unsigned short Ah[2][128 * 32];  // 16 KB
    __shared__ __align__(16) unsigned short Bh[2][128 * 32];  // 16 KB
    const int tid = threadIdx.x;
    const int m0 = blockIdx.x * 128, n0 = blockIdx.y * 128, r = blockIdx.z;
    const int wave = tid >> 6, lane = tid & 63;
    const int wm = (wave >> 1) * 64, wn = (wave & 1) * 64;
    const int lx = lane & 15, qd = lane >> 4;
    const int rl = lane >> 2, cl = (lane & 3) * 8;   // 16 rows/KB, 16B/lane

    f32x4 acc[4][4];
#pragma unroll
    for (int i = 0; i < 4; i++)
#pragma unroll
        for (int j = 0; j < 4; j++) acc[i][j] = (f32x4){0.f, 0.f, 0.f, 0.f};

    const unsigned short* asrc = Xb + (size_t)(m0 + rl) * 1024 + cl;
    const unsigned short* bsrc =
        W1h + (size_t)r * 512 * 1024 + (size_t)(n0 + rl) * 1024 + cl;

#define K1_STAGE(AD, BD, KK)                                         \
    do {                                                             \
        _Pragma("unroll") for (int s = 0; s < 2; s++) {              \
            const int c = wave * 2 + s;                              \
            gll16(asrc + (size_t)c * 16 * 1024 + (KK), (AD) + c * 512); \
            gll16(bsrc + (size_t)c * 16 * 1024 + (KK), (BD) + c * 512); \
        }                                                            \
    } while (0)

    K1_STAGE(Ah[0], Bh[0], 0);
    __syncthreads();
    int p = 0;
    for (int t = 0; t < 32; ++t) {
        if (t < 31) K1_STAGE(Ah[p ^ 1], Bh[p ^ 1], (t + 1) * 32);
        const unsigned short* Ab = Ah[p];
        const unsigned short* Bb = Bh[p];
        bf16x8 fa[4], fb[4];
#pragma unroll
        for (int i = 0; i < 4; i++) {
            fa[i] = *(const bf16x8*)&Ab[(wm + 16 * i + lx) * 32 + 8 * qd];
            fb[i] = *(const bf16x8*)&Bb[(wn + 16 * i + lx) * 32 + 8 * qd];
        }
#pragma unroll
        for (int i = 0; i < 4; i++)
#pragma unroll
            for (int j = 0; j < 4; j++)
                acc[i][j] = __builtin_amdgcn_mfma_f32_16x16x32_bf16(fa[i], fb[j], acc[i][j], 0, 0, 0);
        __syncthreads();  // drains vmcnt: next tile ready; reads of buf p done
        p ^= 1;
    }
#undef K1_STAGE

    unsigned short* Hh = HhA + (size_t)r * 8192 * 512;
#pragma unroll
    for (int i = 0; i < 4; i++)
#pragma unroll
        for (int j = 0; j < 4; j++) {
            const int col = n0 + wn + 16 * j + lx;
#pragma unroll
            for (int p2 = 0; p2 < 4; p2++) {
                const int row = m0 + wm + 16 * i + 4 * qd + p2;
                Hh[(size_t)row * 512 + col] = f2bf(fmaxf(acc[i][j][p2], 0.f));
            }
        }
}

// ---- k1 fallback (fp32 x, reg-staged): unchanged round-4 kernel --------
template <int XBF>
__global__ __launch_bounds__(256) void k1_hbar_mfma(
    const void* __restrict__ Xv,
    const unsigned short* __restrict__ Wh,
    unsigned short* __restrict__ Hh) {
    __shared__ unsigned short Ah[128 * LDT];
    __shared__ unsigned short Bh[128 * LDT];
    const int tid = threadIdx.x;
    const int m0 = blockIdx.x * 128, n0 = blockIdx.y * 128;
    const int wave = tid >> 6, lane = tid & 63;
    const int wm = (wave >> 1) * 64, wn = (wave & 1) * 64;
    const int lx = lane & 15, qd = lane >> 4;
    const int srow = tid >> 1, scol = (tid & 1) * 16;

    f32x4 acc[4][4];
#pragma unroll
    for (int i = 0; i < 4; i++)
#pragma unroll
        for (int j = 0; j < 4; j++) acc[i][j] = (f32x4){0.f, 0.f, 0.f, 0.f};

    const unsigned short* whrow = Wh + (size_t)(n0 + srow) * 1024 + scol;
    unsigned short* ah = &Ah[srow * LDT + scol];
    unsigned short* bh = &Bh[srow * LDT + scol];

    for (int k0 = 0; k0 < 1024; k0 += 32) {
        if (XBF) {
            const unsigned short* xrow =
                (const unsigned short*)Xv + (size_t)(m0 + srow) * 1024 + scol;
            u16x8 a0 = *(const u16x8*)(xrow + k0);
            u16x8 a1 = *(const u16x8*)(xrow + k0 + 8);
            *(u16x8*)(ah) = a0; *(u16x8*)(ah + 8) = a1;
        } else {
            const float* xrow = (const float*)Xv + (size_t)(m0 + srow) * 1024 + scol;
            float4 v0 = *(const float4*)(xrow + k0);
            float4 v1 = *(const float4*)(xrow + k0 + 4);
            float4 v2 = *(const float4*)(xrow + k0 + 8);
            float4 v3 = *(const float4*)(xrow + k0 + 12);
            float vv[16] = {v0.x, v0.y, v0.z, v0.w, v1.x, v1.y, v1.z, v1.w,
                            v2.x, v2.y, v2.z, v2.w, v3.x, v3.y, v3.z, v3.w};
            u16x8 p0, p1;
#pragma unroll
            for (int e = 0; e < 8; e++) p0[e] = f2bf(vv[e]);
#pragma unroll
            for (int e = 0; e < 8; e++) p1[e] = f2bf(vv[8 + e]);
            *(u16x8*)(ah) = p0; *(u16x8*)(ah + 8) = p1;
        }
        u16x8 b0 = *(const u16x8*)(whrow + k0);
        u16x8 b1 = *(const u16x8*)(whrow + k0 + 8);
        *(u16x8*)(bh) = b0; *(u16x8*)(bh + 8) = b1;
        __syncthreads();

        bf16x8 fa[4], fb[4];
#pragma unroll
        for (int i = 0; i < 4; i++) {
            fa[i] = *(const bf16x8*)&Ah[(wm + 16 * i + lx) * LDT + 8 * qd];
            fb[i] = *(const bf16x8*)&Bh[(wn + 16 * i + lx) * LDT + 8 * qd];
        }
#pragma unroll
        for (int i = 0; i < 4; i++)
#pragma unroll
            for (int j = 0; j < 4; j++)
                acc[i][j] = __builtin_amdgcn_mfma_f32_16x16x32_bf16(fa[i], fb[j], acc[i][j], 0, 0, 0);
        __syncthreads();
    }

#pragma unroll
    for (int i = 0; i < 4; i++)
#pragma unroll
        for (int j = 0; j < 4; j++) {
            const int col = n0 + wn + 16 * j + lx;
#pragma unroll
            for (int p = 0; p < 4; p++) {
                const int row = m0 + wm + 16 * i + 4 * qd + p;
                Hh[(size_t)row * 512 + col] = f2bf(fmaxf(acc[i][j][p], 0.f));
            }
        }
}

// ------- k2_allr: scores GEMM + col-softmax + m for 4 r per block -------
// grid (32 b, 16 u-blocks, 2 r-halves). 2-phase dbuf staging; x slice is
// L2-hot across the 4-r loop (all u/z blocks of a b on one XCD via %8).
__global__ __launch_bounds__(256) void k2_allr(
    const unsigned short* __restrict__ HhA,   // [8][8192][512] chunk-local
    const unsigned short* __restrict__ W2h,   // [8][1024][512]
    const float* __restrict__ x, float* __restrict__ m_out, int b0) {
    __shared__ __align__(16) unsigned short Ah[2][256 * 32];  // 32 KB
    __shared__ __align__(16) unsigned short Bh[2][64 * 32];   // 8 KB
    __shared__ float mred[256], sred[256], pred[256];
    const int tid = threadIdx.x;
    const int b_local = blockIdx.x, b = b0 + b_local;
    const int u0 = blockIdx.y * 64;
    const int r_base = blockIdx.z * 4;
    const int wave = tid >> 6, lane = tid & 63;
    const int lx = lane & 15, qd = lane >> 4;
    const int rl = lane >> 2, cl = (lane & 3) * 8;
    const int ub = wave * 16 + rl;                        // B LDS row this lane fills
    const int uperm = 4 * (ub & 15) + (ub >> 4);          // u-permutation

    for (int rr = 0; rr < 4; ++rr) {
        const int r = r_base + rr;
        const unsigned short* asrc =
            HhA + (size_t)r * 8192 * 512 + (size_t)(b_local * 256 + rl) * 512 + cl;
        const unsigned short* bsrc =
            W2h + (size_t)r * 1024 * 512 + (size_t)(u0 + uperm) * 512 + cl;

        f32x4 acc[4][4];
#pragma unroll
        for (int i = 0; i < 4; i++)
#pragma unroll
            for (int j = 0; j < 4; j++) acc[i][j] = (f32x4){0.f, 0.f, 0.f, 0.f};

#define K2_STAGE(AD, BD, KK)                                            \
    do {                                                                \
        _Pragma("unroll") for (int s = 0; s < 4; s++) {                 \
            const int c = wave * 4 + s;                                 \
            gll16(asrc + (size_t)c * 16 * 512 + (KK), (AD) + c * 512);  \
        }                                                               \
        gll16(bsrc + (KK), (BD) + wave * 512);                          \
    } while (0)

        K2_STAGE(Ah[0], Bh[0], 0);
        __syncthreads();
        int p = 0;
        for (int t = 0; t < 16; ++t) {
            if (t < 15) K2_STAGE(Ah[p ^ 1], Bh[p ^ 1], (t + 1) * 32);
            const unsigned short* Ab = Ah[p];
            const unsigned short* Bb = Bh[p];
            bf16x8 fa[4], fb[4];
#pragma unroll
            for (int i = 0; i < 4; i++) {
                fa[i] = *(const bf16x8*)&Ab[(64 * wave + 16 * i + lx) * 32 + 8 * qd];
                fb[i] = *(const bf16x8*)&Bb[(16 * i + lx) * 32 + 8 * qd];
            }
#pragma unroll
            for (int i = 0; i < 4; i++)
#pragma unroll
                for (int j = 0; j < 4; j++)
                    acc[i][j] = __builtin_amdgcn_mfma_f32_16x16x32_bf16(fa[i], fb[j], acc[i][j], 0, 0, 0);
            __syncthreads();
            p ^= 1;
        }
#undef K2_STAGE

        // ---- column max over t: per-lane -> cross-quad -> cross-wave ----
        float cm[4];
#pragma unroll
        for (int j = 0; j < 4; j++) {
            float mx = acc[0][j][0];
#pragma unroll
            for (int i = 0; i < 4; i++)
#pragma unroll
                for (int p2 = 0; p2 < 4; p2++) mx = fmaxf(mx, acc[i][j][p2]);
            mx = fmaxf(mx, __shfl_xor(mx, 16, 64));
            mx = fmaxf(mx, __shfl_xor(mx, 32, 64));
            if (qd == 0) mred[wave * 64 + 16 * j + lx] = mx;
        }
        __syncthreads();
#pragma unroll
        for (int j = 0; j < 4; j++) {
            const int c = 16 * j + lx;
            cm[j] = fmaxf(fmaxf(mred[c], mred[64 + c]),
                          fmaxf(mred[128 + c], mred[192 + c]));
        }

        // ---- exp + weighted sum against x (float4 coalesced, L2-hot) ----
        float ds[4] = {0.f, 0.f, 0.f, 0.f}, pm[4] = {0.f, 0.f, 0.f, 0.f};
        const float* xb = x + (size_t)b * 256 * 1024 + u0 + 4 * lx;
#pragma unroll
        for (int i = 0; i < 4; i++) {
#pragma unroll
            for (int p2 = 0; p2 < 4; p2++) {
                const int t = 64 * wave + 16 * i + 4 * qd + p2;
                float4 xv = *(const float4*)(xb + (size_t)t * 1024);
                float xa[4] = {xv.x, xv.y, xv.z, xv.w};
#pragma unroll
                for (int j = 0; j < 4; j++) {
                    float e = __expf(acc[i][j][p2] - cm[j]);
                    ds[j] += e;
                    pm[j] += e * xa[j];
                }
            }
        }
#pragma unroll
        for (int j = 0; j < 4; j++) {
            ds[j] += __shfl_xor(ds[j], 16, 64);
            ds[j] += __shfl_xor(ds[j], 32, 64);
            pm[j] += __shfl_xor(pm[j], 16, 64);
            pm[j] += __shfl_xor(pm[j], 32, 64);
            if (qd == 0) {
                sred[wave * 64 + 16 * j + lx] = ds[j];
                pred[wave * 64 + 16 * j + lx] = pm[j];
            }
        }
        __syncthreads();
        if (tid < 64) {
            float dsum = sred[tid] + sred[64 + tid] + sred[128 + tid] + sred[192 + tid];
            float psum = pred[tid] + pred[64 + tid] + pred[128 + tid] + pred[192 + tid];
            const int u = u0 + 4 * (tid & 15) + (tid >> 4);  // un-permute
            m_out[(size_t)(r * 128 + b) * 1024 + u] = psum / dsum;
        }
        __syncthreads();  // LDS safe for next r
    }
}

// ------- old k2 (fallback path): round-5 kernel, per-r dispatch ---------
__global__ __launch_bounds__(256) void k2_mfma(
    const unsigned short* __restrict__ Hh,
    const unsigned short* __restrict__ W2h,
    const float* __restrict__ x, float* __restrict__ m_out, int b0, int r) {
    __shared__ __align__(16) unsigned short Ah[256 * 32];
    __shared__ __align__(16) unsigned short Bh[64 * 32];
    __shared__ float mred[256], sred[256], pred[256];
    const int tid = threadIdx.x;
    const int b_local = blockIdx.x, b = b0 + b_local;
    const int u0 = blockIdx.y * 64;
    const int wave = tid >> 6, lane = tid & 63;
    const int lx = lane & 15, qd = lane >> 4;
    const int rl = lane >> 2, cl = (lane & 3) * 8;

    f32x4 acc[4][4];
#pragma unroll
    for (int i = 0; i < 4; i++)
#pragma unroll
        for (int j = 0; j < 4; j++) acc[i][j] = (f32x4){0.f, 0.f, 0.f, 0.f};

    const unsigned short* asrc = Hh + (size_t)(b_local * 256 + rl) * 512 + cl;
    const int ub = wave * 16 + rl;
    const unsigned short* bsrc =
        W2h + (size_t)(u0 + 4 * (ub & 15) + (ub >> 4)) * 512 + cl;

    for (int k0 = 0; k0 < 512; k0 += 32) {
#pragma unroll
        for (int s = 0; s < 4; s++) {
            const int c = wave * 4 + s;
            gll16(asrc + (size_t)c * 16 * 512 + k0, &Ah[c * 512]);
        }
        gll16(bsrc + k0, &Bh[wave * 512]);
        __syncthreads();
        bf16x8 fa[4], fb[4];
#pragma unroll
        for (int i = 0; i < 4; i++) {
            fa[i] = *(const bf16x8*)&Ah[(64 * wave + 16 * i + lx) * 32 + 8 * qd];
            fb[i] = *(const bf16x8*)&Bh[(16 * i + lx) * 32 + 8 * qd];
        }
#pragma unroll
        for (int i = 0; i < 4; i++)
#pragma unroll
            for (int j = 0; j < 4; j++)
                acc[i][j] = __builtin_amdgcn_mfma_f32_16x16x32_bf16(fa[i], fb[j], acc[i][j], 0, 0, 0);
        __syncthreads();
    }

    float cm[4];
#pragma unroll
    for (int j = 0; j < 4; j++) {
        float mx = acc[0][j][0];
#pragma unroll
        for (int i = 0; i < 4; i++)
#pragma unroll
            for (int p = 0; p < 4; p++) mx = fmaxf(mx, acc[i][j][p]);
        mx = fmaxf(mx, __shfl_xor(mx, 16, 64));
        mx = fmaxf(mx, __shfl_xor(mx, 32, 64));
        if (qd == 0) mred[wave * 64 + 16 * j + lx] = mx;
    }
    __syncthreads();
#pragma unroll
    for (int j = 0; j < 4; j++) {
        const int c = 16 * j + lx;
        cm[j] = fmaxf(fmaxf(mred[c], mred[64 + c]), fmaxf(mred[128 + c], mred[192 + c]));
    }

    float ds[4] = {0.f, 0.f, 0.f, 0.f}, pm[4] = {0.f, 0.f, 0.f, 0.f};
    const float* xb = x + (size_t)b * 256 * 1024 + u0 + 4 * lx;
#pragma unroll
    for (int i = 0; i < 4; i++) {
#pragma unroll
        for (int p = 0; p < 4; p++) {
            const int t = 64 * wave + 16 * i + 4 * qd + p;
            float4 xv = *(const float4*)(xb + (size_t)t * 1024);
            float xa[4] = {xv.x, xv.y, xv.z, xv.w};
#pragma unroll
            for (int j = 0; j < 4; j++) {
                float e = __expf(acc[i][j][p] - cm[j]);
                ds[j] += e;
                pm[j] += e * xa[j];
            }
        }
    }
#pragma unroll
    for (int j = 0; j < 4; j++) {
        ds[j] += __shfl_xor(ds[j], 16, 64);
        ds[j] += __shfl_xor(ds[j], 32, 64);
        pm[j] += __shfl_xor(pm[j], 16, 64);
        pm[j] += __shfl_xor(pm[j], 32, 64);
        if (qd == 0) {
            sred[wave * 64 + 16 * j + lx] = ds[j];
            pred[wave * 64 + 16 * j + lx] = pm[j];
        }
    }
    __syncthreads();
    if (tid < 64) {
        float dsum = sred[tid] + sred[64 + tid] + sred[128 + tid] + sred[192 + tid];
        float psum = pred[tid] + pred[64 + tid] + pred[128 + tid] + pred[192 + tid];
        const int u = u0 + 4 * (tid & 15) + (tid >> 4);
        m_out[(size_t)(r * 128 + b) * 1024 + u] = psum / dsum;
    }
}

// ------- k3 (MFMA): votes = m @ cw, cw split [r][n][k] hi/lo, 2-pass -------
__global__ __launch_bounds__(256) void k3_votes_mfma(
    const float* __restrict__ Mb,
    const unsigned short* __restrict__ CWh,
    const unsigned short* __restrict__ CWl,
    float* __restrict__ V) {
    __shared__ unsigned short Ah[128 * LDT];
    __shared__ unsigned short Bh[64 * LDT], Bl[64 * LDT];
    const int tid = threadIdx.x;
    const int r = blockIdx.x, n0 = blockIdx.y * 64;
    const int wave = tid >> 6, lane = tid & 63;
    const int wr = wave >> 1, wc = wave & 1;
    const int lx = lane & 15, qd = lane >> 4;
    const int srow = tid >> 1, scol = (tid & 1) * 16;
    const int brow = tid >> 2, bcol = (tid & 3) * 8;

    const float* arow = Mb + (size_t)(r * 128 + srow) * 1024 + scol;
    const unsigned short* bhrow = CWh + ((size_t)r * 2048 + n0 + brow) * 1024 + bcol;
    const unsigned short* blrow = CWl + ((size_t)r * 2048 + n0 + brow) * 1024 + bcol;

    f32x4 acc[4][2];
#pragma unroll
    for (int i = 0; i < 4; i++)
#pragma unroll
        for (int j = 0; j < 2; j++) acc[i][j] = (f32x4){0.f, 0.f, 0.f, 0.f};

    for (int k0 = 0; k0 < 1024; k0 += 32) {
        float4 v0 = *(const float4*)(arow + k0);
        float4 v1 = *(const float4*)(arow + k0 + 4);
        float4 v2 = *(const float4*)(arow + k0 + 8);
        float4 v3 = *(const float4*)(arow + k0 + 12);
        float vv[16] = {v0.x, v0.y, v0.z, v0.w, v1.x, v1.y, v1.z, v1.w,
                        v2.x, v2.y, v2.z, v2.w, v3.x, v3.y, v3.z, v3.w};
        u16x8 p0, p1;
#pragma unroll
        for (int e = 0; e < 8; e++) p0[e] = f2bf(vv[e]);
#pragma unroll
        for (int e = 0; e < 8; e++) p1[e] = f2bf(vv[8 + e]);
        *(u16x8*)&Ah[srow * LDT + scol] = p0;
        *(u16x8*)&Ah[srow * LDT + scol + 8] = p1;
        *(u16x8*)&Bh[brow * LDT + bcol] = *(const u16x8*)(bhrow + k0);
        *(u16x8*)&Bl[brow * LDT + bcol] = *(const u16x8*)(blrow + k0);
        __syncthreads();

        bf16x8 fa[4], fbh[2], fbl[2];
#pragma unroll
        for (int i = 0; i < 4; i++)
            fa[i] = *(const bf16x8*)&Ah[(64 * wr + 16 * i + lx) * LDT + 8 * qd];
#pragma unroll
        for (int j = 0; j < 2; j++) {
            fbh[j] = *(const bf16x8*)&Bh[(32 * wc + 16 * j + lx) * LDT + 8 * qd];
            fbl[j] = *(const bf16x8*)&Bl[(32 * wc + 16 * j + lx) * LDT + 8 * qd];
        }
#pragma unroll
        for (int i = 0; i < 4; i++)
#pragma unroll
            for (int j = 0; j < 2; j++)
                acc[i][j] = __builtin_amdgcn_mfma_f32_16x16x32_bf16(fa[i], fbh[j], acc[i][j], 0, 0, 0);
#pragma unroll
        for (int i = 0; i < 4; i++)
#pragma unroll
            for (int j = 0; j < 2; j++)
                acc[i][j] = __builtin_amdgcn_mfma_f32_16x16x32_bf16(fa[i], fbl[j], acc[i][j], 0, 0, 0);
        __syncthreads();
    }

#pragma unroll
    for (int i = 0; i < 4; i++)
#pragma unroll
        for (int j = 0; j < 2; j++) {
            const int col = n0 + 32 * wc + 16 * j + lx;
#pragma unroll
            for (int p = 0; p < 4; p++) {
                const int row = 64 * wr + 16 * i + 4 * qd + p;
                V[((size_t)r * 128 + row) * 2048 + col] = acc[i][j][p];
            }
        }
}

// ---------------- k3 fallback: fp32 VALU (small-ws path) ----------------
__global__ __launch_bounds__(256) void k3_votes(const float* __restrict__ Mb,
                                                const float* __restrict__ CW,
                                                float* __restrict__ V) {
    __shared__ float As[16][132];
    __shared__ float Bs[16][132];
    const int tid = threadIdx.x;
    const int r = blockIdx.z;
    const int n0 = blockIdx.x * 128;
    const float* A = Mb + (size_t)r * 128 * 1024;
    const float* Bm = CW + (size_t)r * 1024 * 2048;
    float* C = V + (size_t)r * 128 * 2048;
    const int ty = tid >> 4, tx = tid & 15;
    const int k4 = (tid & 3) * 4, row = tid >> 2;
    const int n4 = (tid & 31) * 4, krow = tid >> 5;

    float acc[8][8];
#pragma unroll
    for (int i = 0; i < 8; i++)
#pragma unroll
        for (int j = 0; j < 8; j++) acc[i][j] = 0.f;

    for (int k0 = 0; k0 < 1024; k0 += 16) {
#pragma unroll
        for (int rr = 0; rr < 2; rr++) {
            const int m = row + rr * 64;
            float4 av = *(const float4*)(A + (size_t)m * 1024 + k0 + k4);
            As[k4 + 0][m] = av.x; As[k4 + 1][m] = av.y;
            As[k4 + 2][m] = av.z; As[k4 + 3][m] = av.w;
            const int k = krow + rr * 8;
            float4 bv = *(const float4*)(Bm + (size_t)(k0 + k) * 2048 + n0 + n4);
            *(float4*)(&Bs[k][n4]) = bv;
        }
        __syncthreads();
#pragma unroll
        for (int k = 0; k < 16; k++) {
            float a[8], b[8];
            *(float4*)(a)     = *(const float4*)(&As[k][ty * 8]);
            *(float4*)(a + 4) = *(const float4*)(&As[k][ty * 8 + 4]);
            *(float4*)(b)     = *(const float4*)(&Bs[k][tx * 8]);
            *(float4*)(b + 4) = *(const float4*)(&Bs[k][tx * 8 + 4]);
#pragma unroll
            for (int i = 0; i < 8; i++)
#pragma unroll
                for (int j = 0; j < 8; j++) acc[i][j] += a[i] * b[j];
        }
        __syncthreads();
    }
#pragma unroll
    for (int i = 0; i < 8; i++) {
        const int m = ty * 8 + i;
#pragma unroll
        for (int j = 0; j < 8; j += 4) {
            float4 v;
            v.x = acc[i][j + 0]; v.y = acc[i][j + 1];
            v.z = acc[i][j + 2]; v.w = acc[i][j + 3];
            *(float4*)(C + (size_t)m * 2048 + n0 + tx * 8 + j) = v;
        }
    }
}

// ---------------- k4: dynamic routing ----------------
__global__ __launch_bounds__(256) void k4_routing(const float* __restrict__ V,
                                                  float* __restrict__ out) {
    __shared__ float logits[8 * 128];
    __shared__ float route[8 * 128];
    __shared__ float preact[128 * 16];
    __shared__ float act[128 * 16];
    __shared__ float fred[128];
    const int b = blockIdx.x, tid = threadIdx.x;
    const float* vb = V + (size_t)b * 2048;

    for (int i = tid; i < 1024; i += 256) logits[i] = 0.f;
    __syncthreads();

    for (int it = 0; it < 3; it++) {
        {
            const int r = tid >> 5, g = tid & 31;
            float l[4];
#pragma unroll
            for (int q = 0; q < 4; q++) l[q] = logits[r * 128 + g + q * 32];
            float mx = fmaxf(fmaxf(l[0], l[1]), fmaxf(l[2], l[3]));
            for (int msk = 16; msk; msk >>= 1) mx = fmaxf(mx, __shfl_xor(mx, msk, 32));
            float e[4], s = 0.f;
#pragma unroll
            for (int q = 0; q < 4; q++) { e[q] = expf(l[q] - mx); s += e[q]; }
            for (int msk = 16; msk; msk >>= 1) s += __shfl_xor(s, msk, 32);
            float inv = 1.f / s;
#pragma unroll
            for (int q = 0; q < 4; q++) route[r * 128 + g + q * 32] = e[q] * inv;
        }
        __syncthreads();
        for (int i = tid; i < 2048; i += 256) {
            const int c = i >> 4;
            float a = 0.f;
#pragma unroll
            for (int r = 0; r < 8; r++)
                a += route[r * 128 + c] * vb[(size_t)r * 128 * 2048 + i];
            preact[i] = a;
        }
        __syncthreads();
        if (tid < 128) {
            float n2 = 0.f;
#pragma unroll
            for (int o = 0; o < 16; o++) { float p = preact[tid * 16 + o]; n2 += p * p; }
            fred[tid] = sqrtf(n2) / (1.f + n2);
        }
        __syncthreads();
        for (int i = tid; i < 2048; i += 256) act[i] = preact[i] * fred[i >> 4];
        __syncthreads();
        for (int i = tid; i < 1024; i += 256) {
            const int r = i >> 7, c = i & 127;
            float d = 0.f;
#pragma unroll
            for (int o = 0; o < 16; o++)
                d += vb[(size_t)r * 128 * 2048 + c * 16 + o] * act[c * 16 + o];
            logits[i] += d;
        }
        __syncthreads();
    }
    if (tid < 128) {
        float n2 = 0.f;
#pragma unroll
        for (int o = 0; o < 16; o++) { float a = act[tid * 16 + o]; n2 += a * a; }
        out[(size_t)b * 128 + tid] = sqrtf(n2);
    }
}

extern "C" void kernel_launch(void* const* d_in, const int* in_sizes, int n_in,
                              void* d_out, int out_size, void* d_ws, size_t ws_size,
                              hipStream_t stream) {
    const float* x   = (const float*)d_in[0];
    const float* WS1 = (const float*)d_in[1];
    const float* WS2 = (const float*)d_in[2];
    const float* cw  = (const float*)d_in[3];
    float* out = (float*)d_out;

    char* ws = (char*)d_ws;
    float* m_buf = (float*)ws;                                      // 4 MiB
    float* votes = (float*)(ws + ((size_t)4 << 20));                // 8 MiB
    unsigned short* W1h = (unsigned short*)(ws + ((size_t)12 << 20)); // 8 MiB
    unsigned short* W2h = (unsigned short*)(ws + ((size_t)20 << 20)); // 8 MiB

    const bool use_cw  = ws_size >= ((size_t)124 << 20);
    const bool use_xbf = ws_size >= ((size_t)188 << 20);

    const int nW4 = (8 * 512 * 1024) / 4;
    k0_hi<<<dim3((nW4 + 255) / 256), dim3(256), 0, stream>>>(WS1, W1h, nW4);
    k0_hi<<<dim3((nW4 + 255) / 256), dim3(256), 0, stream>>>(WS2, W2h, nW4);

    if (use_xbf) {
        // --- big-ws path: Xbf @28, HhA @92 (overlaid by CWh/CWl post-loop) ---
        unsigned short* Xbf = (unsigned short*)(ws + ((size_t)28 << 20)); // 64 MiB
        unsigned short* HhA = (unsigned short*)(ws + ((size_t)92 << 20)); // 64 MiB
        unsigned short* CWh = (unsigned short*)(ws + ((size_t)92 << 20)); // 32 MiB
        unsigned short* CWl = (unsigned short*)(ws + ((size_t)124 << 20)); // 32 MiB

        const int nX4 = (128 * 256 * 1024) / 4;
        k0_hi<<<dim3((nX4 + 255) / 256), dim3(256), 0, stream>>>(x, Xbf, nX4);

        for (int b0 = 0; b0 < 128; b0 += 32) {
            k1_all<<<dim3(64, 4, 8), dim3(256), 0, stream>>>(
                Xbf + (size_t)b0 * 256 * 1024, W1h, HhA);
            k2_allr<<<dim3(32, 16, 2), dim3(256), 0, stream>>>(
                HhA, W2h, x, m_buf, b0);
        }
        // HhA dead; overlay CWh/CWl and finish
        k0_tsplit<<<dim3(32, 16, 8), dim3(256), 0, stream>>>(cw, CWh, CWl);
        k3_votes_mfma<<<dim3(8, 32), dim3(256), 0, stream>>>(m_buf, CWh, CWl, votes);
    } else {
        // --- fallback path: round-4/5 flow ---
        unsigned short* CWh = (unsigned short*)(ws + ((size_t)28 << 20));
        unsigned short* CWl = (unsigned short*)(ws + ((size_t)60 << 20));
        const size_t hh_off = use_cw ? ((size_t)92 << 20) : ((size_t)28 << 20);
        unsigned short* Hh = (unsigned short*)(ws + hh_off);

        int CB = 128;
        {
            const size_t perb = (size_t)256 << 10;
            if (ws_size < hh_off + 128 * perb) {
                size_t avail = (ws_size > hh_off) ? (ws_size - hh_off) : perb;
                CB = (int)(avail / perb);
                if (CB < 1) CB = 1;
                if (CB > 128) CB = 128;
            }
        }

        if (use_cw)
            k0_tsplit<<<dim3(32, 16, 8), dim3(256), 0, stream>>>(cw, CWh, CWl);

        for (int b0 = 0; b0 < 128; b0 += CB) {
            const int bc = (128 - b0 < CB) ? (128 - b0) : CB;
            for (int r = 0; r < 8; r++) {
                k1_hbar_mfma<0><<<dim3(bc * 2, 4), dim3(256), 0, stream>>>(
                    (const void*)(x + (size_t)b0 * 256 * 1024),
                    W1h + (size_t)r * 512 * 1024, Hh);
                k2_mfma<<<dim3(bc, 16), dim3(256), 0, stream>>>(
                    Hh, W2h + (size_t)r * 1024 * 512, x, m_buf, b0, r);
            }
        }
        if (use_cw)
            k3_votes_mfma<<<dim3(8, 32), dim3(256), 0, stream>>>(m_buf, CWh, CWl, votes);
        else
            k3_votes<<<dim3(16, 1, 8), dim3(256), 0, stream>>>(m_buf, cw, votes);
    }
    k4_routing<<<dim3(128), dim3(256), 0, stream>>>(votes, out);
}